// Round 13
// baseline (151.700 us; speedup 1.0000x reference)
//
#include <hip/hip_runtime.h>
#include <hip/hip_bf16.h>
#include <stdint.h>

typedef __attribute__((ext_vector_type(8))) short  short8;   // 8 bf16 (4 VGPR) MFMA A/B frag
typedef __attribute__((ext_vector_type(4))) short  short4v;
typedef __attribute__((ext_vector_type(4))) float  float4v;  // 16x16 MFMA C/D frag
typedef __attribute__((ext_vector_type(16))) float f32x16;   // 32x32 MFMA C/D frag
typedef __attribute__((ext_vector_type(2))) unsigned int uint2v;

#define MFMA16(a, b, c) __builtin_amdgcn_mfma_f32_16x16x32_bf16((a), (b), (c), 0, 0, 0)
#define MFMA32(a, b, c) __builtin_amdgcn_mfma_f32_32x32x16_bf16((a), (b), (c), 0, 0, 0)

#define S_LEN  4096
#define NBATCH 4
#define EMB    1024
#define DD     64
#define NROWS  (NBATCH * S_LEN)  // 16384
#define SCL2   0.1803368801111204f  // (1/sqrt(64)) * log2(e), folded into Wq at wcvt

#define AS1 const __attribute__((address_space(1))) unsigned int*
#define AS3 __attribute__((address_space(3))) unsigned int*

static __device__ __forceinline__ short f2bf(float f) {
  uint32_t u = __float_as_uint(f);
  return (short)((u + 0x7FFFu + ((u >> 16) & 1u)) >> 16);
}
static __device__ __forceinline__ unsigned pk2(float a, float b) {
  union { __hip_bfloat162 h; unsigned u; } z;
  z.h = __float22bfloat162_rn(make_float2(a, b));
  return z.u;
}
static __device__ __forceinline__ short8 cvt8(float4v a, float4v b) {
  union { unsigned u[4]; short8 s; } z;
  z.u[0] = pk2(a[0], a[1]); z.u[1] = pk2(a[2], a[3]);
  z.u[2] = pk2(b[0], b[1]); z.u[3] = pk2(b[2], b[3]);
  return z.s;
}

// ============ Kernel 0: W fp32 -> bf16, reordered into 32-k panels ============
// Wb2 layout: [32 panels][192 rows][32 k] bf16; rows 0-63=Wq (pre-scaled by
// SCL2 -> scores arrive in log2 domain), 64-127=Wk, 128-191=Wv.
__global__ void wcvt_kernel(const float* __restrict__ Wq, const float* __restrict__ Wk,
                            const float* __restrict__ Wv, short* __restrict__ Wb2) {
  const int t   = blockIdx.x * 256 + threadIdx.x;  // 0..24575, 8 elems each
  const int row = t >> 7;
  const int k   = (t & 127) * 8;
  const float* src = (row < 64) ? (Wq + (size_t)row * EMB)
                   : (row < 128) ? (Wk + (size_t)(row - 64) * EMB)
                                 : (Wv + (size_t)(row - 128) * EMB);
  const float sc = (row < 64) ? SCL2 : 1.0f;
  float4v a = *(const float4v*)(src + k);
  float4v b = *(const float4v*)(src + k + 4);
#pragma unroll
  for (int i = 0; i < 4; ++i) { a[i] *= sc; b[i] *= sc; }
  *(short8*)(Wb2 + (((k >> 5) * 192 + row) << 5) + (k & 31)) = cvt8(a, b);
}

// ======================= Kernel 1: QKV projection GEMM =======================
// Round 19 (KEPT -- verified -6 us): M32 shape + both-sides As swizzle.
// R11's direct counters showed SQ_LDS_BANK_CONFLICT = 8.9M cyc on As
// fragment reads (addr mod 128 took only 4 values). Fix: within each 1KB
// slot, row r's k-chunk kb lives at kb ^ ((r>>1)&3); global source is
// pre-swizzled (global_load_lds writes linearly), read applies the same XOR.
__global__ __launch_bounds__(256, 2) void qkv_kernel(
    const float* __restrict__ x, const short* __restrict__ Wb2,
    short* __restrict__ Qb, short* __restrict__ Kb, short* __restrict__ Vt) {
  __shared__ float As[2][2048];   // 2 x 8 KB  (32 rows x 64 k fp32, slot order)
  __shared__ short Bs[2][12288];  // 2 x 24 KB (2 panels x 192 x 32 bf16, identity)

  const int tid  = threadIdx.x;
  const int w    = tid >> 6;
  const int lane = tid & 63;
  const int ln   = lane & 15;
  const int quad = lane >> 4;
  const int m0   = blockIdx.x * 32;
  const int wr   = w & 1;
  const int wc   = w >> 1;

  const int tA0 = 2 * w, tA1 = 2 * w + 1;
  // k-block swizzled by row bits (lane>>3)&3 -- see header comment.
  const int kbs = (lane & 3) ^ ((lane >> 3) & 3);
  const float* xA0 = x + (size_t)(m0 + ((tA0 >> 2) << 4) + (lane >> 2)) * EMB
                       + ((tA0 & 3) * 4 + kbs) * 4;
  const float* xA1 = x + (size_t)(m0 + ((tA1 >> 2) << 4) + (lane >> 2)) * EMB
                       + ((tA1 & 3) * 4 + kbs) * 4;
  const short* wB = Wb2 + (size_t)(6 * w) * 512 + lane * 8;

#define STAGE(S, BUF) do {                                                      \
    __builtin_amdgcn_global_load_lds((AS1)(xA0 + (S) * 64),                     \
        (AS3)&As[BUF][tA0 * 256], 16, 0, 0);                                    \
    __builtin_amdgcn_global_load_lds((AS1)(xA1 + (S) * 64),                     \
        (AS3)&As[BUF][tA1 * 256], 16, 0, 0);                                    \
    _Pragma("unroll")                                                           \
    for (int j = 0; j < 6; ++j)                                                 \
      __builtin_amdgcn_global_load_lds((AS1)(wB + (size_t)(S) * 12288 + j * 512),\
          (AS3)&Bs[BUF][(6 * w + j) * 512], 16, 0, 0);                          \
  } while (0)

  const float4v zz = {0.f, 0.f, 0.f, 0.f};
  float4v acc[6] = {zz, zz, zz, zz, zz, zz};

  const int sw = (ln >> 1) & 3;   // read-side swizzle term

  STAGE(0, 0);
  int buf = 0;
  for (int s = 0; s < 16; ++s) {
    __syncthreads();                       // drains this buf's DMA (vmcnt 0)
    if (s + 1 < 16) STAGE(s + 1, buf ^ 1); // overlaps with compute below
    short8 aF[2];
#pragma unroll
    for (int h = 0; h < 2; ++h) {
      const int rb = (wr * 4 + 2 * h + (quad >> 1)) * 256 + ln * 16;
      const float4v lo = *(const float4v*)&As[buf][rb + ((((quad & 1) * 2)    ) ^ sw) * 4];
      const float4v hi = *(const float4v*)&As[buf][rb + ((((quad & 1) * 2) + 1) ^ sw) * 4];
      aF[h] = cvt8(lo, hi);
    }
#pragma unroll
    for (int f = 0; f < 6; ++f) {
      const int cf = wc * 6 + f;
      const short8 b0 = *(const short8*)&Bs[buf][(cf * 16 + ln) * 32 + quad * 8];
      const short8 b1 = *(const short8*)&Bs[buf][6144 + (cf * 16 + ln) * 32 + quad * 8];
      if (wc == 0 || f < 2) {
        acc[f] = MFMA16(aF[0], b0, acc[f]);
        acc[f] = MFMA16(aF[1], b1, acc[f]);
      } else {  // V frags: operand swap -> transposed output
        acc[f] = MFMA16(b0, aF[0], acc[f]);
        acc[f] = MFMA16(b1, aF[1], acc[f]);
      }
    }
    buf ^= 1;
  }
#undef STAGE

  const int b  = m0 >> 12;
  const int sb = m0 & (S_LEN - 1);
  if (wc == 0) {
#pragma unroll
    for (int f = 0; f < 6; ++f)
#pragma unroll
      for (int r = 0; r < 4; ++r) {
        const int row = m0 + wr * 16 + quad * 4 + r;
        if (f < 4) Qb[(size_t)row * DD + f * 16 + ln] = f2bf(acc[f][r]);
        else       Kb[(size_t)row * DD + (f - 4) * 16 + ln] = f2bf(acc[f][r]);
      }
  } else {
#pragma unroll
    for (int f = 0; f < 2; ++f)
#pragma unroll
      for (int r = 0; r < 4; ++r) {
        const int row = m0 + wr * 16 + quad * 4 + r;
        Kb[(size_t)row * DD + 32 + f * 16 + ln] = f2bf(acc[f][r]);
      }
#pragma unroll
    for (int f = 2; f < 6; ++f)
#pragma unroll
      for (int r = 0; r < 4; ++r) {
        const int d = (f - 2) * 16 + quad * 4 + r;
        Vt[((size_t)b * DD + d) * S_LEN + sb + wr * 16 + ln] = f2bf(acc[f][r]);
      }
  }
}

// ======================= Kernel 2: causal flash attention =======================
// Round 20: 2-tile ILP unroll on the R10 band-pair engine.
// Arithmetic from R10: ~5,850 cyc/iter measured vs ~500 cyc issue cost --
// both pipes <20% busy, 2 waves/SIMD fixed by the register bucket. The
// untried axis is INTRA-WAVE ILP: process tiles (it, it+8) per iteration.
// The two tiles' QK/exp/pack phases are independent -> tile1's QK (MFMA
// pipe) overlaps tile0's exp+pack (VALU pipe) within one wave (m114:
// separate pipes co-schedule). PV accumulate-chains into shared o pipeline
// fine. Regs ~220 total (arch ~125 + acc ~96) stays in the 129-256 bucket:
// occupancy unchanged by design; spill tripwire = FETCH explosion.
__global__ __launch_bounds__(512, 2) void attn_kernel(
    const short* __restrict__ Qb, const short* __restrict__ Kb,
    const short* __restrict__ Vt, float* __restrict__ out) {
  __shared__ float sbuf[8][2048];   // 64 KB: one band-pass of 8-wave partials
  __shared__ float llds[8][32];

  const int tid  = threadIdx.x;
  const int w    = tid >> 6;
  const int lane = tid & 63;
  const int l31  = lane & 31;
  const int hi   = lane >> 5;
  const int g    = blockIdx.x;
  const int b    = g & 3;
  const int k2   = g >> 2;          // pair index 0..63
  const short* Kbase = Kb + (size_t)b * S_LEN * DD;
  const short* Vbase = Vt + (size_t)b * DD * S_LEN;

  const int bandA = 2 * k2, bandB = 2 * k2 + 1;
  const int qbA   = bandA * 32;
  const int qgA   = b * S_LEN + qbA;          // band A global row base
  const int qglobA = qbA + l31;
  const int qglobB = qbA + 32 + l31;

  // Q for both bands: lane holds Q[row l31][dk*16 + hi*8 + 0..7]
  short8 qA[4], qB[4];
#pragma unroll
  for (int dk = 0; dk < 4; ++dk) {
    qA[dk] = *(const short8*)(Qb + (size_t)(qgA + l31) * DD + dk * 16 + hi * 8);
    qB[dk] = *(const short8*)(Qb + (size_t)(qgA + 32 + l31) * DD + dk * 16 + hi * 8);
  }

  f32x16 oA0, oA1, oB0, oB1, zz16;
#pragma unroll
  for (int e = 0; e < 16; ++e) { oA0[e] = oA1[e] = oB0[e] = oB1[e] = 0.f; zz16[e] = 0.f; }
  float lpA = 0.f, lpB = 0.f;

  const int itN = bandB + 1;   // tiles 0..bandB

#define LOADKV(KF, VF, KV0) do {                                               \
    _Pragma("unroll")                                                          \
    for (int dk = 0; dk < 4; ++dk)                                             \
      KF[dk] = *(const short8*)(Kbase + (size_t)((KV0) + l31) * DD + dk * 16 + hi * 8); \
    _Pragma("unroll")                                                          \
    for (int df = 0; df < 2; ++df)                                             \
      _Pragma("unroll")                                                        \
      for (int kc = 0; kc < 2; ++kc)                                           \
        VF[df][kc] = *(const short8*)(Vbase + (size_t)(df * 32 + l31) * S_LEN + (KV0) + kc * 16 + hi * 8); \
  } while (0)

    // ---- shared per-band engine: QK chain, exp2(+mask), pack, PV ----
#define BAND_STEP(QV, OV0, OV1, LP, QGLOB, DIAG, SKIP, KF, VF, KV0) do {       \
    if (!(SKIP)) {                                                             \
      f32x16 s = MFMA32(KF[0], (QV)[0], zz16);                                 \
      _Pragma("unroll")                                                        \
      for (int dk = 1; dk < 4; ++dk) s = MFMA32(KF[dk], (QV)[dk], s);          \
      if (DIAG) {                                                              \
        _Pragma("unroll")                                                      \
        for (int e = 0; e < 16; ++e) {                                         \
          const int kvl = (e & 3) + 8 * (e >> 2) + 4 * hi;                     \
          float e0 = __builtin_amdgcn_exp2f(fminf(s[e], 60.0f));               \
          if ((KV0) + kvl > (QGLOB)) e0 = 0.f;                                 \
          s[e] = e0; (LP) += e0;                                               \
        }                                                                      \
      } else {                                                                 \
        _Pragma("unroll")                                                      \
        for (int e = 0; e < 16; ++e) {                                         \
          float e0 = __builtin_amdgcn_exp2f(fminf(s[e], 60.0f));               \
          s[e] = e0; (LP) += e0;                                               \
        }                                                                      \
      }                                                                        \
      unsigned ua, ub, uc, ud, ue, uf2, ug, uh;                                \
      asm("v_cvt_pk_bf16_f32 %0, %1, %2" : "=v"(ua) : "v"(s[0]),  "v"(s[1]));  \
      asm("v_cvt_pk_bf16_f32 %0, %1, %2" : "=v"(ub) : "v"(s[2]),  "v"(s[3]));  \
      asm("v_cvt_pk_bf16_f32 %0, %1, %2" : "=v"(uc) : "v"(s[4]),  "v"(s[5]));  \
      asm("v_cvt_pk_bf16_f32 %0, %1, %2" : "=v"(ud) : "v"(s[6]),  "v"(s[7]));  \
      asm("v_cvt_pk_bf16_f32 %0, %1, %2" : "=v"(ue) : "v"(s[8]),  "v"(s[9]));  \
      asm("v_cvt_pk_bf16_f32 %0, %1, %2" : "=v"(uf2): "v"(s[10]), "v"(s[11])); \
      asm("v_cvt_pk_bf16_f32 %0, %1, %2" : "=v"(ug) : "v"(s[12]), "v"(s[13])); \
      asm("v_cvt_pk_bf16_f32 %0, %1, %2" : "=v"(uh) : "v"(s[14]), "v"(s[15])); \
      uint2v r0 = __builtin_amdgcn_permlane32_swap(ua, uc, false, false);      \
      uint2v r1 = __builtin_amdgcn_permlane32_swap(ub, ud, false, false);      \
      uint2v r2 = __builtin_amdgcn_permlane32_swap(ue, ug, false, false);      \
      uint2v r3 = __builtin_amdgcn_permlane32_swap(uf2, uh, false, false);     \
      union { unsigned uu[4]; short8 s8; } p0, p1;                             \
      p0.uu[0] = r0[0]; p0.uu[1] = r1[0]; p0.uu[2] = r0[1]; p0.uu[3] = r1[1];  \
      p1.uu[0] = r2[0]; p1.uu[1] = r3[0]; p1.uu[2] = r2[1]; p1.uu[3] = r3[1];  \
      (OV0) = MFMA32(p0.s8, VF[0][0], (OV0));                                  \
      (OV0) = MFMA32(p1.s8, VF[0][1], (OV0));                                  \
      (OV1) = MFMA32(p0.s8, VF[1][0], (OV1));                                  \
      (OV1) = MFMA32(p1.s8, VF[1][1], (OV1));                                  \
    }                                                                          \
  } while (0)

  short8 kf0[4], kf1[4];
  short8 vf0[2][2], vf1[2][2];

  int it = w;
  for (; it + 8 < itN; it += 16) {
    const int kv0 = it * 32, kv1 = (it + 8) * 32;
    LOADKV(kf0, vf0, kv0);
    LOADKV(kf1, vf1, kv1);
    // Interleave-friendly order: tile0's exp/pack (VALU) overlaps tile1's QK (MFMA).
    BAND_STEP(qA, oA0, oA1, lpA, qglobA, it == bandA,       it > bandA,       kf0, vf0, kv0);
    BAND_STEP(qA, oA0, oA1, lpA, qglobA, (it + 8) == bandA, (it + 8) > bandA, kf1, vf1, kv1);
    BAND_STEP(qB, oB0, oB1, lpB, qglobB, it == bandB,       false,            kf0, vf0, kv0);
    BAND_STEP(qB, oB0, oB1, lpB, qglobB, (it + 8) == bandB, false,            kf1, vf1, kv1);
  }
  if (it < itN) {
    const int kv0 = it * 32;
    LOADKV(kf0, vf0, kv0);
    BAND_STEP(qA, oA0, oA1, lpA, qglobA, it == bandA, it > bandA, kf0, vf0, kv0);
    BAND_STEP(qB, oB0, oB1, lpB, qglobB, it == bandB, false,      kf0, vf0, kv0);
  }
#undef BAND_STEP
#undef LOADKV

  // ---- epilogue: two 32-q passes (band A then band B), reusing sbuf ----
#define EPILOG(OV0, OV1, LP, ROW0) do {                                        \
    float lpt = (LP) + __shfl_xor((LP), 32);                                   \
    float* pw = &sbuf[w][0];                                                   \
    _Pragma("unroll")                                                          \
    for (int e = 0; e < 16; ++e) {                                             \
      const int ql = (e & 3) + 8 * (e >> 2) + 4 * hi;                          \
      pw[ql * 64 + l31]      = (OV0)[e];                                       \
      pw[ql * 64 + 32 + l31] = (OV1)[e];                                       \
    }                                                                          \
    if (hi == 0) llds[w][l31] = lpt;                                           \
    __syncthreads();                                                           \
    _Pragma("unroll")                                                          \
    for (int jx = 0; jx < 4; ++jx) {                                           \
      const int idx = tid + jx * 512;                                          \
      const int row = idx >> 6, col = idx & 63;                                \
      float sum = 0.f, lt = 0.f;                                               \
      _Pragma("unroll")                                                        \
      for (int wi = 0; wi < 8; ++wi) {                                         \
        sum += sbuf[wi][row * 64 + col];                                       \
        lt  += llds[wi][row];                                                  \
      }                                                                        \
      out[(size_t)((ROW0) + row) * DD + col] = sum * __builtin_amdgcn_rcpf(lt);\
    }                                                                          \
    __syncthreads();                                                           \
  } while (0)

  EPILOG(oA0, oA1, lpA, qgA);
  EPILOG(oB0, oB1, lpB, qgA + 32);
#undef EPILOG
}

extern "C" void kernel_launch(void* const* d_in, const int* in_sizes, int n_in,
                              void* d_out, int out_size, void* d_ws, size_t ws_size,
                              hipStream_t stream) {
  const float* x  = (const float*)d_in[0];
  const float* Wq = (const float*)d_in[1];
  const float* Wk = (const float*)d_in[2];
  const float* Wv = (const float*)d_in[3];

  short* Qb  = (short*)d_ws;                       // 2 MB
  short* Kb  = Qb + (size_t)NROWS * DD;            // 2 MB
  short* Vt  = Kb + (size_t)NROWS * DD;            // 2 MB  [b][d][s]
  short* Wb2 = Vt + (size_t)NROWS * DD;            // 384 KB panels

  wcvt_kernel<<<dim3(96), dim3(256), 0, stream>>>(Wq, Wk, Wv, Wb2);
  qkv_kernel<<<dim3(NROWS / 32), dim3(256), 0, stream>>>(x, Wb2, Qb, Kb, Vt);
  attn_kernel<<<dim3(NBATCH * 64), dim3(512), 0, stream>>>(Qb, Kb, Vt, (float*)d_out);
}

// Round 14
// 150.354 us; speedup vs baseline: 1.0090x; 1.0090x over previous
//
#include <hip/hip_runtime.h>
#include <hip/hip_bf16.h>
#include <stdint.h>

typedef __attribute__((ext_vector_type(8))) short  short8;   // 8 bf16 (4 VGPR) MFMA A/B frag
typedef __attribute__((ext_vector_type(4))) short  short4v;
typedef __attribute__((ext_vector_type(4))) float  float4v;  // 16x16 MFMA C/D frag
typedef __attribute__((ext_vector_type(16))) float f32x16;   // 32x32 MFMA C/D frag
typedef __attribute__((ext_vector_type(2))) unsigned int uint2v;

#define MFMA16(a, b, c) __builtin_amdgcn_mfma_f32_16x16x32_bf16((a), (b), (c), 0, 0, 0)
#define MFMA32(a, b, c) __builtin_amdgcn_mfma_f32_32x32x16_bf16((a), (b), (c), 0, 0, 0)

#define S_LEN  4096
#define NBATCH 4
#define EMB    1024
#define DD     64
#define NROWS  (NBATCH * S_LEN)  // 16384
#define SCL2   0.1803368801111204f  // (1/sqrt(64)) * log2(e), folded into Wq at wcvt

#define AS1 const __attribute__((address_space(1))) unsigned int*
#define AS3 __attribute__((address_space(3))) unsigned int*

static __device__ __forceinline__ short f2bf(float f) {
  uint32_t u = __float_as_uint(f);
  return (short)((u + 0x7FFFu + ((u >> 16) & 1u)) >> 16);
}
static __device__ __forceinline__ unsigned pk2(float a, float b) {
  union { __hip_bfloat162 h; unsigned u; } z;
  z.h = __float22bfloat162_rn(make_float2(a, b));
  return z.u;
}
static __device__ __forceinline__ short8 cvt8(float4v a, float4v b) {
  union { unsigned u[4]; short8 s; } z;
  z.u[0] = pk2(a[0], a[1]); z.u[1] = pk2(a[2], a[3]);
  z.u[2] = pk2(b[0], b[1]); z.u[3] = pk2(b[2], b[3]);
  return z.s;
}

// ============ Kernel 0: W fp32 -> bf16, reordered into 32-k panels ============
// Wb2 layout: [32 panels][192 rows][32 k] bf16; rows 0-63=Wq (pre-scaled by
// SCL2 -> scores arrive in log2 domain), 64-127=Wk, 128-191=Wv.
__global__ void wcvt_kernel(const float* __restrict__ Wq, const float* __restrict__ Wk,
                            const float* __restrict__ Wv, short* __restrict__ Wb2) {
  const int t   = blockIdx.x * 256 + threadIdx.x;  // 0..24575, 8 elems each
  const int row = t >> 7;
  const int k   = (t & 127) * 8;
  const float* src = (row < 64) ? (Wq + (size_t)row * EMB)
                   : (row < 128) ? (Wk + (size_t)(row - 64) * EMB)
                                 : (Wv + (size_t)(row - 128) * EMB);
  const float sc = (row < 64) ? SCL2 : 1.0f;
  float4v a = *(const float4v*)(src + k);
  float4v b = *(const float4v*)(src + k + 4);
#pragma unroll
  for (int i = 0; i < 4; ++i) { a[i] *= sc; b[i] *= sc; }
  *(short8*)(Wb2 + (((k >> 5) * 192 + row) << 5) + (k & 31)) = cvt8(a, b);
}

// ======================= Kernel 1: QKV projection GEMM =======================
// Round 19 (KEPT -- verified -6 us): M32 shape + both-sides As swizzle.
// R11's direct counters showed SQ_LDS_BANK_CONFLICT = 8.9M cyc on As
// fragment reads (addr mod 128 took only 4 values). Fix: within each 1KB
// slot, row r's k-chunk kb lives at kb ^ ((r>>1)&3); global source is
// pre-swizzled (global_load_lds writes linearly), read applies the same XOR.
__global__ __launch_bounds__(256, 2) void qkv_kernel(
    const float* __restrict__ x, const short* __restrict__ Wb2,
    short* __restrict__ Qb, short* __restrict__ Kb, short* __restrict__ Vt) {
  __shared__ float As[2][2048];   // 2 x 8 KB  (32 rows x 64 k fp32, slot order)
  __shared__ short Bs[2][12288];  // 2 x 24 KB (2 panels x 192 x 32 bf16, identity)

  const int tid  = threadIdx.x;
  const int w    = tid >> 6;
  const int lane = tid & 63;
  const int ln   = lane & 15;
  const int quad = lane >> 4;
  const int m0   = blockIdx.x * 32;
  const int wr   = w & 1;
  const int wc   = w >> 1;

  const int tA0 = 2 * w, tA1 = 2 * w + 1;
  // k-block swizzled by row bits (lane>>3)&3 -- see header comment.
  const int kbs = (lane & 3) ^ ((lane >> 3) & 3);
  const float* xA0 = x + (size_t)(m0 + ((tA0 >> 2) << 4) + (lane >> 2)) * EMB
                       + ((tA0 & 3) * 4 + kbs) * 4;
  const float* xA1 = x + (size_t)(m0 + ((tA1 >> 2) << 4) + (lane >> 2)) * EMB
                       + ((tA1 & 3) * 4 + kbs) * 4;
  const short* wB = Wb2 + (size_t)(6 * w) * 512 + lane * 8;

#define STAGE(S, BUF) do {                                                      \
    __builtin_amdgcn_global_load_lds((AS1)(xA0 + (S) * 64),                     \
        (AS3)&As[BUF][tA0 * 256], 16, 0, 0);                                    \
    __builtin_amdgcn_global_load_lds((AS1)(xA1 + (S) * 64),                     \
        (AS3)&As[BUF][tA1 * 256], 16, 0, 0);                                    \
    _Pragma("unroll")                                                           \
    for (int j = 0; j < 6; ++j)                                                 \
      __builtin_amdgcn_global_load_lds((AS1)(wB + (size_t)(S) * 12288 + j * 512),\
          (AS3)&Bs[BUF][(6 * w + j) * 512], 16, 0, 0);                          \
  } while (0)

  const float4v zz = {0.f, 0.f, 0.f, 0.f};
  float4v acc[6] = {zz, zz, zz, zz, zz, zz};

  const int sw = (ln >> 1) & 3;   // read-side swizzle term

  STAGE(0, 0);
  int buf = 0;
  for (int s = 0; s < 16; ++s) {
    __syncthreads();                       // drains this buf's DMA (vmcnt 0)
    if (s + 1 < 16) STAGE(s + 1, buf ^ 1); // overlaps with compute below
    short8 aF[2];
#pragma unroll
    for (int h = 0; h < 2; ++h) {
      const int rb = (wr * 4 + 2 * h + (quad >> 1)) * 256 + ln * 16;
      const float4v lo = *(const float4v*)&As[buf][rb + ((((quad & 1) * 2)    ) ^ sw) * 4];
      const float4v hi = *(const float4v*)&As[buf][rb + ((((quad & 1) * 2) + 1) ^ sw) * 4];
      aF[h] = cvt8(lo, hi);
    }
#pragma unroll
    for (int f = 0; f < 6; ++f) {
      const int cf = wc * 6 + f;
      const short8 b0 = *(const short8*)&Bs[buf][(cf * 16 + ln) * 32 + quad * 8];
      const short8 b1 = *(const short8*)&Bs[buf][6144 + (cf * 16 + ln) * 32 + quad * 8];
      if (wc == 0 || f < 2) {
        acc[f] = MFMA16(aF[0], b0, acc[f]);
        acc[f] = MFMA16(aF[1], b1, acc[f]);
      } else {  // V frags: operand swap -> transposed output
        acc[f] = MFMA16(b0, aF[0], acc[f]);
        acc[f] = MFMA16(b1, aF[1], acc[f]);
      }
    }
    buf ^= 1;
  }
#undef STAGE

  const int b  = m0 >> 12;
  const int sb = m0 & (S_LEN - 1);
  if (wc == 0) {
#pragma unroll
    for (int f = 0; f < 6; ++f)
#pragma unroll
      for (int r = 0; r < 4; ++r) {
        const int row = m0 + wr * 16 + quad * 4 + r;
        if (f < 4) Qb[(size_t)row * DD + f * 16 + ln] = f2bf(acc[f][r]);
        else       Kb[(size_t)row * DD + (f - 4) * 16 + ln] = f2bf(acc[f][r]);
      }
  } else {
#pragma unroll
    for (int f = 0; f < 2; ++f)
#pragma unroll
      for (int r = 0; r < 4; ++r) {
        const int row = m0 + wr * 16 + quad * 4 + r;
        Kb[(size_t)row * DD + 32 + f * 16 + ln] = f2bf(acc[f][r]);
      }
#pragma unroll
    for (int f = 2; f < 6; ++f)
#pragma unroll
      for (int r = 0; r < 4; ++r) {
        const int d = (f - 2) * 16 + quad * 4 + r;
        Vt[((size_t)b * DD + d) * S_LEN + sb + wr * 16 + ln] = f2bf(acc[f][r]);
      }
  }
}

// ======================= Kernel 2: causal flash attention =======================
// Round 21: BRANCHLESS fused band-pair loop (single-buffer, R12 registers).
// R13's extra-buffer ILP regressed (+3.5 us): more arch pressure, no chain
// cut. The overlooked serializer: 4 runtime branches per tile (if(DIAG) x2,
// if(SKIP)) chop the body into small basic blocks -- the scheduler cannot
// overlap band A's exp/pack (VALU) with band B's QK (MFMA) across them.
// They are removable by algebra: for sub-diagonal tiles the causal predicate
// kv0+kvl > qglob is automatically FALSE, so unconditional masked-exp is
// exact for every tile; and the A-side SKIP on tile bandB can go -- the mask
// zeroes that whole contribution (one redundant tile-step per block).
// New body: one straight-line block per tile: QK_A + QK_B back-to-back (two
// independent 4-deep MFMA chains), one masked-exp pass for both, pack+PV A,
// pack+PV B. Zero extra K/V buffers vs R12 (sA+sB live = +16 acc, ~190
// total, same 129-256 bucket -> occupancy unchanged).
__global__ __launch_bounds__(512, 2) void attn_kernel(
    const short* __restrict__ Qb, const short* __restrict__ Kb,
    const short* __restrict__ Vt, float* __restrict__ out) {
  __shared__ float sbuf[8][2048];   // 64 KB: one band-pass of 8-wave partials
  __shared__ float llds[8][32];

  const int tid  = threadIdx.x;
  const int w    = tid >> 6;
  const int lane = tid & 63;
  const int l31  = lane & 31;
  const int hi   = lane >> 5;
  const int g    = blockIdx.x;
  const int b    = g & 3;
  const int k2   = g >> 2;          // pair index 0..63
  const short* Kbase = Kb + (size_t)b * S_LEN * DD;
  const short* Vbase = Vt + (size_t)b * DD * S_LEN;

  const int bandA = 2 * k2, bandB = 2 * k2 + 1;
  const int qbA   = bandA * 32;
  const int qgA   = b * S_LEN + qbA;          // band A global row base
  const int qglobA = qbA + l31;
  const int qglobB = qbA + 32 + l31;

  // Q for both bands: lane holds Q[row l31][dk*16 + hi*8 + 0..7]
  short8 qA[4], qB[4];
#pragma unroll
  for (int dk = 0; dk < 4; ++dk) {
    qA[dk] = *(const short8*)(Qb + (size_t)(qgA + l31) * DD + dk * 16 + hi * 8);
    qB[dk] = *(const short8*)(Qb + (size_t)(qgA + 32 + l31) * DD + dk * 16 + hi * 8);
  }

  f32x16 oA0, oA1, oB0, oB1, zz16;
#pragma unroll
  for (int e = 0; e < 16; ++e) { oA0[e] = oA1[e] = oB0[e] = oB1[e] = 0.f; zz16[e] = 0.f; }
  float lpA = 0.f, lpB = 0.f;

  const int itN = bandB + 1;   // tiles 0..bandB

  for (int it = w; it < itN; it += 8) {
    const int kv0 = it * 32;
    short8 kf[4];
#pragma unroll
    for (int dk = 0; dk < 4; ++dk)
      kf[dk] = *(const short8*)(Kbase + (size_t)(kv0 + l31) * DD + dk * 16 + hi * 8);
    short8 vf[2][2];
#pragma unroll
    for (int df = 0; df < 2; ++df)
#pragma unroll
      for (int kc = 0; kc < 2; ++kc)
        vf[df][kc] = *(const short8*)(Vbase + (size_t)(df * 32 + l31) * S_LEN + kv0 + kc * 16 + hi * 8);

    // QK for BOTH bands back-to-back: two independent 4-deep MFMA chains.
    f32x16 sA = MFMA32(kf[0], qA[0], zz16);
    f32x16 sB = MFMA32(kf[0], qB[0], zz16);
#pragma unroll
    for (int dk = 1; dk < 4; ++dk) {
      sA = MFMA32(kf[dk], qA[dk], sA);
      sB = MFMA32(kf[dk], qB[dk], sB);
    }

    // Unconditional masked exp2 (exact: predicate auto-false below diagonal).
#pragma unroll
    for (int e = 0; e < 16; ++e) {
      const int kvg = kv0 + (e & 3) + 8 * (e >> 2) + 4 * hi;
      float eA = __builtin_amdgcn_exp2f(fminf(sA[e], 60.0f));
      float eB = __builtin_amdgcn_exp2f(fminf(sB[e], 60.0f));
      if (kvg > qglobA) eA = 0.f;
      if (kvg > qglobB) eB = 0.f;
      sA[e] = eA; sB[e] = eB;
      lpA += eA; lpB += eB;
    }

    // ---- in-register P->bf16 A-frags + PV (mapping HW-verified in R7) ----
#define PACK_PV(S, OV0, OV1) do {                                              \
      unsigned ua, ub, uc, ud, ue, uf2, ug, uh;                                \
      asm("v_cvt_pk_bf16_f32 %0, %1, %2" : "=v"(ua) : "v"((S)[0]),  "v"((S)[1]));  \
      asm("v_cvt_pk_bf16_f32 %0, %1, %2" : "=v"(ub) : "v"((S)[2]),  "v"((S)[3]));  \
      asm("v_cvt_pk_bf16_f32 %0, %1, %2" : "=v"(uc) : "v"((S)[4]),  "v"((S)[5]));  \
      asm("v_cvt_pk_bf16_f32 %0, %1, %2" : "=v"(ud) : "v"((S)[6]),  "v"((S)[7]));  \
      asm("v_cvt_pk_bf16_f32 %0, %1, %2" : "=v"(ue) : "v"((S)[8]),  "v"((S)[9]));  \
      asm("v_cvt_pk_bf16_f32 %0, %1, %2" : "=v"(uf2): "v"((S)[10]), "v"((S)[11])); \
      asm("v_cvt_pk_bf16_f32 %0, %1, %2" : "=v"(ug) : "v"((S)[12]), "v"((S)[13])); \
      asm("v_cvt_pk_bf16_f32 %0, %1, %2" : "=v"(uh) : "v"((S)[14]), "v"((S)[15])); \
      uint2v r0 = __builtin_amdgcn_permlane32_swap(ua, uc, false, false);      \
      uint2v r1 = __builtin_amdgcn_permlane32_swap(ub, ud, false, false);      \
      uint2v r2 = __builtin_amdgcn_permlane32_swap(ue, ug, false, false);      \
      uint2v r3 = __builtin_amdgcn_permlane32_swap(uf2, uh, false, false);     \
      union { unsigned uu[4]; short8 s8; } p0, p1;                             \
      p0.uu[0] = r0[0]; p0.uu[1] = r1[0]; p0.uu[2] = r0[1]; p0.uu[3] = r1[1];  \
      p1.uu[0] = r2[0]; p1.uu[1] = r3[0]; p1.uu[2] = r2[1]; p1.uu[3] = r3[1];  \
      (OV0) = MFMA32(p0.s8, vf[0][0], (OV0));                                  \
      (OV0) = MFMA32(p1.s8, vf[0][1], (OV0));                                  \
      (OV1) = MFMA32(p0.s8, vf[1][0], (OV1));                                  \
      (OV1) = MFMA32(p1.s8, vf[1][1], (OV1));                                  \
    } while (0)

    PACK_PV(sA, oA0, oA1);
    PACK_PV(sB, oB0, oB1);
#undef PACK_PV
  }

  // ---- epilogue: two 32-q passes (band A then band B), reusing sbuf ----
#define EPILOG(OV0, OV1, LP, ROW0) do {                                        \
    float lpt = (LP) + __shfl_xor((LP), 32);                                   \
    float* pw = &sbuf[w][0];                                                   \
    _Pragma("unroll")                                                          \
    for (int e = 0; e < 16; ++e) {                                             \
      const int ql = (e & 3) + 8 * (e >> 2) + 4 * hi;                          \
      pw[ql * 64 + l31]      = (OV0)[e];                                       \
      pw[ql * 64 + 32 + l31] = (OV1)[e];                                       \
    }                                                                          \
    if (hi == 0) llds[w][l31] = lpt;                                           \
    __syncthreads();                                                           \
    _Pragma("unroll")                                                          \
    for (int jx = 0; jx < 4; ++jx) {                                           \
      const int idx = tid + jx * 512;                                          \
      const int row = idx >> 6, col = idx & 63;                                \
      float sum = 0.f, lt = 0.f;                                               \
      _Pragma("unroll")                                                        \
      for (int wi = 0; wi < 8; ++wi) {                                         \
        sum += sbuf[wi][row * 64 + col];                                       \
        lt  += llds[wi][row];                                                  \
      }                                                                        \
      out[(size_t)((ROW0) + row) * DD + col] = sum * __builtin_amdgcn_rcpf(lt);\
    }                                                                          \
    __syncthreads();                                                           \
  } while (0)

  EPILOG(oA0, oA1, lpA, qgA);
  EPILOG(oB0, oB1, lpB, qgA + 32);
#undef EPILOG
}

extern "C" void kernel_launch(void* const* d_in, const int* in_sizes, int n_in,
                              void* d_out, int out_size, void* d_ws, size_t ws_size,
                              hipStream_t stream) {
  const float* x  = (const float*)d_in[0];
  const float* Wq = (const float*)d_in[1];
  const float* Wk = (const float*)d_in[2];
  const float* Wv = (const float*)d_in[3];

  short* Qb  = (short*)d_ws;                       // 2 MB
  short* Kb  = Qb + (size_t)NROWS * DD;            // 2 MB
  short* Vt  = Kb + (size_t)NROWS * DD;            // 2 MB  [b][d][s]
  short* Wb2 = Vt + (size_t)NROWS * DD;            // 384 KB panels

  wcvt_kernel<<<dim3(96), dim3(256), 0, stream>>>(Wq, Wk, Wv, Wb2);
  qkv_kernel<<<dim3(NROWS / 32), dim3(256), 0, stream>>>(x, Wb2, Qb, Kb, Vt);
  attn_kernel<<<dim3(NBATCH * 64), dim3(512), 0, stream>>>(Qb, Kb, Vt, (float*)d_out);
}

// Round 15
// 148.984 us; speedup vs baseline: 1.0182x; 1.0092x over previous
//
#include <hip/hip_runtime.h>
#include <hip/hip_bf16.h>
#include <stdint.h>

typedef __attribute__((ext_vector_type(8))) short  short8;   // 8 bf16 (4 VGPR) MFMA A/B frag
typedef __attribute__((ext_vector_type(4))) short  short4v;
typedef __attribute__((ext_vector_type(4))) float  float4v;  // 16x16 MFMA C/D frag
typedef __attribute__((ext_vector_type(16))) float f32x16;   // 32x32 MFMA C/D frag
typedef __attribute__((ext_vector_type(2))) unsigned int uint2v;

#define MFMA16(a, b, c) __builtin_amdgcn_mfma_f32_16x16x32_bf16((a), (b), (c), 0, 0, 0)
#define MFMA32(a, b, c) __builtin_amdgcn_mfma_f32_32x32x16_bf16((a), (b), (c), 0, 0, 0)

#define S_LEN  4096
#define NBATCH 4
#define EMB    1024
#define DD     64
#define NROWS  (NBATCH * S_LEN)  // 16384
#define SCL2   0.1803368801111204f  // (1/sqrt(64)) * log2(e), folded into Wq at wcvt

#define AS1 const __attribute__((address_space(1))) unsigned int*
#define AS3 __attribute__((address_space(3))) unsigned int*

static __device__ __forceinline__ short f2bf(float f) {
  uint32_t u = __float_as_uint(f);
  return (short)((u + 0x7FFFu + ((u >> 16) & 1u)) >> 16);
}
static __device__ __forceinline__ unsigned pk2(float a, float b) {
  union { __hip_bfloat162 h; unsigned u; } z;
  z.h = __float22bfloat162_rn(make_float2(a, b));
  return z.u;
}
static __device__ __forceinline__ short8 cvt8(float4v a, float4v b) {
  union { unsigned u[4]; short8 s; } z;
  z.u[0] = pk2(a[0], a[1]); z.u[1] = pk2(a[2], a[3]);
  z.u[2] = pk2(b[0], b[1]); z.u[3] = pk2(b[2], b[3]);
  return z.s;
}

// ============ Kernel 0: W fp32 -> bf16, reordered into 32-k panels ============
// Wb2 layout: [32 panels][192 rows][32 k] bf16; rows 0-63=Wq (pre-scaled by
// SCL2 -> scores arrive in log2 domain), 64-127=Wk, 128-191=Wv.
__global__ void wcvt_kernel(const float* __restrict__ Wq, const float* __restrict__ Wk,
                            const float* __restrict__ Wv, short* __restrict__ Wb2) {
  const int t   = blockIdx.x * 256 + threadIdx.x;  // 0..24575, 8 elems each
  const int row = t >> 7;
  const int k   = (t & 127) * 8;
  const float* src = (row < 64) ? (Wq + (size_t)row * EMB)
                   : (row < 128) ? (Wk + (size_t)(row - 64) * EMB)
                                 : (Wv + (size_t)(row - 128) * EMB);
  const float sc = (row < 64) ? SCL2 : 1.0f;
  float4v a = *(const float4v*)(src + k);
  float4v b = *(const float4v*)(src + k + 4);
#pragma unroll
  for (int i = 0; i < 4; ++i) { a[i] *= sc; b[i] *= sc; }
  *(short8*)(Wb2 + (((k >> 5) * 192 + row) << 5) + (k & 31)) = cvt8(a, b);
}

// ======================= Kernel 1: QKV projection GEMM =======================
// Round 19 (KEPT -- verified -6 us): M32 shape + both-sides As swizzle.
// R11's direct counters showed SQ_LDS_BANK_CONFLICT = 8.9M cyc on As
// fragment reads (addr mod 128 took only 4 values). Fix: within each 1KB
// slot, row r's k-chunk kb lives at kb ^ ((r>>1)&3); global source is
// pre-swizzled (global_load_lds writes linearly), read applies the same XOR.
__global__ __launch_bounds__(256, 2) void qkv_kernel(
    const float* __restrict__ x, const short* __restrict__ Wb2,
    short* __restrict__ Qb, short* __restrict__ Kb, short* __restrict__ Vt) {
  __shared__ float As[2][2048];   // 2 x 8 KB  (32 rows x 64 k fp32, slot order)
  __shared__ short Bs[2][12288];  // 2 x 24 KB (2 panels x 192 x 32 bf16, identity)

  const int tid  = threadIdx.x;
  const int w    = tid >> 6;
  const int lane = tid & 63;
  const int ln   = lane & 15;
  const int quad = lane >> 4;
  const int m0   = blockIdx.x * 32;
  const int wr   = w & 1;
  const int wc   = w >> 1;

  const int tA0 = 2 * w, tA1 = 2 * w + 1;
  // k-block swizzled by row bits (lane>>3)&3 -- see header comment.
  const int kbs = (lane & 3) ^ ((lane >> 3) & 3);
  const float* xA0 = x + (size_t)(m0 + ((tA0 >> 2) << 4) + (lane >> 2)) * EMB
                       + ((tA0 & 3) * 4 + kbs) * 4;
  const float* xA1 = x + (size_t)(m0 + ((tA1 >> 2) << 4) + (lane >> 2)) * EMB
                       + ((tA1 & 3) * 4 + kbs) * 4;
  const short* wB = Wb2 + (size_t)(6 * w) * 512 + lane * 8;

#define STAGE(S, BUF) do {                                                      \
    __builtin_amdgcn_global_load_lds((AS1)(xA0 + (S) * 64),                     \
        (AS3)&As[BUF][tA0 * 256], 16, 0, 0);                                    \
    __builtin_amdgcn_global_load_lds((AS1)(xA1 + (S) * 64),                     \
        (AS3)&As[BUF][tA1 * 256], 16, 0, 0);                                    \
    _Pragma("unroll")                                                           \
    for (int j = 0; j < 6; ++j)                                                 \
      __builtin_amdgcn_global_load_lds((AS1)(wB + (size_t)(S) * 12288 + j * 512),\
          (AS3)&Bs[BUF][(6 * w + j) * 512], 16, 0, 0);                          \
  } while (0)

  const float4v zz = {0.f, 0.f, 0.f, 0.f};
  float4v acc[6] = {zz, zz, zz, zz, zz, zz};

  const int sw = (ln >> 1) & 3;   // read-side swizzle term

  STAGE(0, 0);
  int buf = 0;
  for (int s = 0; s < 16; ++s) {
    __syncthreads();                       // drains this buf's DMA (vmcnt 0)
    if (s + 1 < 16) STAGE(s + 1, buf ^ 1); // overlaps with compute below
    short8 aF[2];
#pragma unroll
    for (int h = 0; h < 2; ++h) {
      const int rb = (wr * 4 + 2 * h + (quad >> 1)) * 256 + ln * 16;
      const float4v lo = *(const float4v*)&As[buf][rb + ((((quad & 1) * 2)    ) ^ sw) * 4];
      const float4v hi = *(const float4v*)&As[buf][rb + ((((quad & 1) * 2) + 1) ^ sw) * 4];
      aF[h] = cvt8(lo, hi);
    }
#pragma unroll
    for (int f = 0; f < 6; ++f) {
      const int cf = wc * 6 + f;
      const short8 b0 = *(const short8*)&Bs[buf][(cf * 16 + ln) * 32 + quad * 8];
      const short8 b1 = *(const short8*)&Bs[buf][6144 + (cf * 16 + ln) * 32 + quad * 8];
      if (wc == 0 || f < 2) {
        acc[f] = MFMA16(aF[0], b0, acc[f]);
        acc[f] = MFMA16(aF[1], b1, acc[f]);
      } else {  // V frags: operand swap -> transposed output
        acc[f] = MFMA16(b0, aF[0], acc[f]);
        acc[f] = MFMA16(b1, aF[1], acc[f]);
      }
    }
    buf ^= 1;
  }
#undef STAGE

  const int b  = m0 >> 12;
  const int sb = m0 & (S_LEN - 1);
  if (wc == 0) {
#pragma unroll
    for (int f = 0; f < 6; ++f)
#pragma unroll
      for (int r = 0; r < 4; ++r) {
        const int row = m0 + wr * 16 + quad * 4 + r;
        if (f < 4) Qb[(size_t)row * DD + f * 16 + ln] = f2bf(acc[f][r]);
        else       Kb[(size_t)row * DD + (f - 4) * 16 + ln] = f2bf(acc[f][r]);
      }
  } else {
#pragma unroll
    for (int f = 0; f < 2; ++f)
#pragma unroll
      for (int r = 0; r < 4; ++r) {
        const int row = m0 + wr * 16 + quad * 4 + r;
        Kb[(size_t)row * DD + 32 + f * 16 + ln] = f2bf(acc[f][r]);
      }
#pragma unroll
    for (int f = 2; f < 6; ++f)
#pragma unroll
      for (int r = 0; r < 4; ++r) {
        const int d = (f - 2) * 16 + quad * 4 + r;
        Vt[((size_t)b * DD + d) * S_LEN + sb + wr * 16 + ln] = f2bf(acc[f][r]);
      }
  }
}

// ======================= Kernel 2: causal flash attention =======================
// FINAL (lock-in of the R12/round-17 engine -- best verified total 148.2 us):
// band-pair K/V reuse (each tile's K/V loaded once, used for 2 bands) +
// in-register swapped-QK^T 32x32 softmax (R7-verified permlane mapping).
// Falsified-attn-mechanism ledger (each mechanically executed, all neutral
// or regressive): K-prefetch (R6), occupancy 19->31% (R9), critical-path
// halving (R9), L2-traffic halving (R10 -- kept for its neutrality + fewer
// loads), 2-tile ILP buffers (R13, +3.5), branchless fusion (R14, +2.2).
// attn's ~39 us floor is not explained by available counters (MfmaUtil ~7%,
// VALU ~18%, HBM ~3%, conflicts ~0, no spill); only the LDS->register
// softmax rewrite (R7, +10%) ever moved it.
__global__ __launch_bounds__(512, 2) void attn_kernel(
    const short* __restrict__ Qb, const short* __restrict__ Kb,
    const short* __restrict__ Vt, float* __restrict__ out) {
  __shared__ float sbuf[8][2048];   // 64 KB: one band-pass of 8-wave partials
  __shared__ float llds[8][32];

  const int tid  = threadIdx.x;
  const int w    = tid >> 6;
  const int lane = tid & 63;
  const int l31  = lane & 31;
  const int hi   = lane >> 5;
  const int g    = blockIdx.x;
  const int b    = g & 3;
  const int k2   = g >> 2;          // pair index 0..63
  const short* Kbase = Kb + (size_t)b * S_LEN * DD;
  const short* Vbase = Vt + (size_t)b * DD * S_LEN;

  const int bandA = 2 * k2, bandB = 2 * k2 + 1;
  const int qbA   = bandA * 32;
  const int qgA   = b * S_LEN + qbA;          // band A global row base
  const int qglobA = qbA + l31;
  const int qglobB = qbA + 32 + l31;

  // Q for both bands: lane holds Q[row l31][dk*16 + hi*8 + 0..7]
  short8 qA[4], qB[4];
#pragma unroll
  for (int dk = 0; dk < 4; ++dk) {
    qA[dk] = *(const short8*)(Qb + (size_t)(qgA + l31) * DD + dk * 16 + hi * 8);
    qB[dk] = *(const short8*)(Qb + (size_t)(qgA + 32 + l31) * DD + dk * 16 + hi * 8);
  }

  f32x16 oA0, oA1, oB0, oB1, zz16;
#pragma unroll
  for (int e = 0; e < 16; ++e) { oA0[e] = oA1[e] = oB0[e] = oB1[e] = 0.f; zz16[e] = 0.f; }
  float lpA = 0.f, lpB = 0.f;

  const int itN = bandB + 1;   // tiles 0..bandB

  for (int it = w; it < itN; it += 8) {
    const int kv0 = it * 32;
    short8 kf[4];
#pragma unroll
    for (int dk = 0; dk < 4; ++dk)
      kf[dk] = *(const short8*)(Kbase + (size_t)(kv0 + l31) * DD + dk * 16 + hi * 8);
    short8 vf[2][2];
#pragma unroll
    for (int df = 0; df < 2; ++df)
#pragma unroll
      for (int kc = 0; kc < 2; ++kc)
        vf[df][kc] = *(const short8*)(Vbase + (size_t)(df * 32 + l31) * S_LEN + kv0 + kc * 16 + hi * 8);

    // ---- shared per-band engine: QK chain, exp2(+mask), pack, PV ----
#define BAND_STEP(QV, OV0, OV1, LP, QGLOB, DIAG, SKIP) do {                    \
    if (!(SKIP)) {                                                             \
      f32x16 s = MFMA32(kf[0], (QV)[0], zz16);                                 \
      _Pragma("unroll")                                                        \
      for (int dk = 1; dk < 4; ++dk) s = MFMA32(kf[dk], (QV)[dk], s);          \
      if (DIAG) {                                                              \
        _Pragma("unroll")                                                      \
        for (int e = 0; e < 16; ++e) {                                         \
          const int kvl = (e & 3) + 8 * (e >> 2) + 4 * hi;                     \
          float e0 = __builtin_amdgcn_exp2f(fminf(s[e], 60.0f));               \
          if (kv0 + kvl > (QGLOB)) e0 = 0.f;                                   \
          s[e] = e0; (LP) += e0;                                               \
        }                                                                      \
      } else {                                                                 \
        _Pragma("unroll")                                                      \
        for (int e = 0; e < 16; ++e) {                                         \
          float e0 = __builtin_amdgcn_exp2f(fminf(s[e], 60.0f));               \
          s[e] = e0; (LP) += e0;                                               \
        }                                                                      \
      }                                                                        \
      unsigned ua, ub, uc, ud, ue, uf2, ug, uh;                                \
      asm("v_cvt_pk_bf16_f32 %0, %1, %2" : "=v"(ua) : "v"(s[0]),  "v"(s[1]));  \
      asm("v_cvt_pk_bf16_f32 %0, %1, %2" : "=v"(ub) : "v"(s[2]),  "v"(s[3]));  \
      asm("v_cvt_pk_bf16_f32 %0, %1, %2" : "=v"(uc) : "v"(s[4]),  "v"(s[5]));  \
      asm("v_cvt_pk_bf16_f32 %0, %1, %2" : "=v"(ud) : "v"(s[6]),  "v"(s[7]));  \
      asm("v_cvt_pk_bf16_f32 %0, %1, %2" : "=v"(ue) : "v"(s[8]),  "v"(s[9]));  \
      asm("v_cvt_pk_bf16_f32 %0, %1, %2" : "=v"(uf2): "v"(s[10]), "v"(s[11])); \
      asm("v_cvt_pk_bf16_f32 %0, %1, %2" : "=v"(ug) : "v"(s[12]), "v"(s[13])); \
      asm("v_cvt_pk_bf16_f32 %0, %1, %2" : "=v"(uh) : "v"(s[14]), "v"(s[15])); \
      uint2v r0 = __builtin_amdgcn_permlane32_swap(ua, uc, false, false);      \
      uint2v r1 = __builtin_amdgcn_permlane32_swap(ub, ud, false, false);      \
      uint2v r2 = __builtin_amdgcn_permlane32_swap(ue, ug, false, false);      \
      uint2v r3 = __builtin_amdgcn_permlane32_swap(uf2, uh, false, false);     \
      union { unsigned uu[4]; short8 s8; } p0, p1;                             \
      p0.uu[0] = r0[0]; p0.uu[1] = r1[0]; p0.uu[2] = r0[1]; p0.uu[3] = r1[1];  \
      p1.uu[0] = r2[0]; p1.uu[1] = r3[0]; p1.uu[2] = r2[1]; p1.uu[3] = r3[1];  \
      (OV0) = MFMA32(p0.s8, vf[0][0], (OV0));                                  \
      (OV0) = MFMA32(p1.s8, vf[0][1], (OV0));                                  \
      (OV1) = MFMA32(p0.s8, vf[1][0], (OV1));                                  \
      (OV1) = MFMA32(p1.s8, vf[1][1], (OV1));                                  \
    }                                                                          \
  } while (0)

    BAND_STEP(qA, oA0, oA1, lpA, qglobA, it == bandA, it > bandA);
    BAND_STEP(qB, oB0, oB1, lpB, qglobB, it == bandB, false);
#undef BAND_STEP
  }

  // ---- epilogue: two 32-q passes (band A then band B), reusing sbuf ----
#define EPILOG(OV0, OV1, LP, ROW0) do {                                        \
    float lpt = (LP) + __shfl_xor((LP), 32);                                   \
    float* pw = &sbuf[w][0];                                                   \
    _Pragma("unroll")                                                          \
    for (int e = 0; e < 16; ++e) {                                             \
      const int ql = (e & 3) + 8 * (e >> 2) + 4 * hi;                          \
      pw[ql * 64 + l31]      = (OV0)[e];                                       \
      pw[ql * 64 + 32 + l31] = (OV1)[e];                                       \
    }                                                                          \
    if (hi == 0) llds[w][l31] = lpt;                                           \
    __syncthreads();                                                           \
    _Pragma("unroll")                                                          \
    for (int jx = 0; jx < 4; ++jx) {                                           \
      const int idx = tid + jx * 512;                                          \
      const int row = idx >> 6, col = idx & 63;                                \
      float sum = 0.f, lt = 0.f;                                               \
      _Pragma("unroll")                                                        \
      for (int wi = 0; wi < 8; ++wi) {                                         \
        sum += sbuf[wi][row * 64 + col];                                       \
        lt  += llds[wi][row];                                                  \
      }                                                                        \
      out[(size_t)((ROW0) + row) * DD + col] = sum * __builtin_amdgcn_rcpf(lt);\
    }                                                                          \
    __syncthreads();                                                           \
  } while (0)

  EPILOG(oA0, oA1, lpA, qgA);
  EPILOG(oB0, oB1, lpB, qgA + 32);
#undef EPILOG
}

extern "C" void kernel_launch(void* const* d_in, const int* in_sizes, int n_in,
                              void* d_out, int out_size, void* d_ws, size_t ws_size,
                              hipStream_t stream) {
  const float* x  = (const float*)d_in[0];
  const float* Wq = (const float*)d_in[1];
  const float* Wk = (const float*)d_in[2];
  const float* Wv = (const float*)d_in[3];

  short* Qb  = (short*)d_ws;                       // 2 MB
  short* Kb  = Qb + (size_t)NROWS * DD;            // 2 MB
  short* Vt  = Kb + (size_t)NROWS * DD;            // 2 MB  [b][d][s]
  short* Wb2 = Vt + (size_t)NROWS * DD;            // 384 KB panels

  wcvt_kernel<<<dim3(96), dim3(256), 0, stream>>>(Wq, Wk, Wv, Wb2);
  qkv_kernel<<<dim3(NROWS / 32), dim3(256), 0, stream>>>(x, Wb2, Qb, Kb, Vt);
  attn_kernel<<<dim3(NBATCH * 64), dim3(512), 0, stream>>>(Qb, Kb, Vt, (float*)d_out);
}